// Round 2
// baseline (82.059 us; speedup 1.0000x reference)
//
#include <hip/hip_runtime.h>
#include <math.h>

// PCEN: x [16,1,128,2048] f32, params alpha/delta/r [128] (log-space).
// smoother m[t] = (1-s) m[t-1] + s x[t], m[-1] = x[0]  (== reference's dense
// triangular matmul, verified algebraically).
// out[b, t, band] = (x*smooth + d)^rr - d^rr
//
// R2: 16 waves/block (1024 thr) = 8 bands x 2 T-halves. Halves the serial
// scan chains (32->16 per lane) and doubles waves/SIMD (2->4). Cross-half
// carry via one LDS exchange; decay applied closed-form: g^(16*lane).

#define T_LEN   2048
#define NBANDS  128
#define PL      2184   // 128*17 + 8 pad (words): lane-row stride 17 -> conflict-free

__global__ __launch_bounds__(1024) void pcen_kernel(
    const float* __restrict__ x,
    const float* __restrict__ alpha,
    const float* __restrict__ delta,
    const float* __restrict__ r,
    float* __restrict__ out)
{
    __shared__ float tile[8 * PL];
    __shared__ float carr[8];

    const int tid  = threadIdx.x;
    const int w    = tid >> 6;     // wave 0..15
    const int lane = tid & 63;
    const int wb   = w & 7;        // band within group
    const int h    = w >> 3;       // T-half 0/1
    const int bid  = blockIdx.x;
    const int b    = bid >> 4;
    const int bg   = bid & 15;
    const int band = bg * 8 + wb;

    // s = (sqrt(1+4*T_VAL^2)-1) / (2*T_VAL^2), fp32 like the reference
    const float s = (sqrtf(262145.0f) - 1.0f) / 131072.0f;
    const float g = 1.0f - s;
    float g16 = g * g;   // ^2
    g16 *= g16;          // ^4
    g16 *= g16;          // ^8
    g16 *= g16;          // ^16

    const float a    = __expf(alpha[band]);
    const float dd   = __expf(delta[band]);
    const float rr   = __expf(r[band]);
    const float dpow = __expf(rr * delta[band]);   // d^rr
    const float LOG_EPS = -11.512925465f;          // log(1e-5)
    const float INV_EPS = 1.0e5f;

    const size_t row = ((size_t)b * NBANDS + band) * T_LEN;
    const float* xp  = x + row + (size_t)h * 1024 + (size_t)lane * 16;

    // ---- load 16 contiguous x into registers (4x float4) ----
    float xs[16];
    #pragma unroll
    for (int j = 0; j < 4; ++j) {
        const float4 v4 = *reinterpret_cast<const float4*>(xp + j * 4);
        xs[j*4+0] = v4.x; xs[j*4+1] = v4.y; xs[j*4+2] = v4.z; xs[j*4+3] = v4.w;
    }

    // ---- local serial scan for lane carry (h0/lane0 seeds m[-1] = x[0]) ----
    float m = (h == 0 && lane == 0) ? xs[0] : 0.0f;
    #pragma unroll
    for (int k = 0; k < 16; ++k) m = fmaf(g, m, s * xs[k]);

    // ---- decayed Kogge-Stone inclusive scan of lane carries ----
    float v = m;
    float f = g16;
    #pragma unroll
    for (int off = 1; off < 64; off <<= 1) {
        float u = __shfl_up(v, off, 64);
        if (lane >= off) v = fmaf(f, u, v);
        f = f * f;
    }
    // exclusive carry into this lane's chunk
    float carry = __shfl_up(v, 1, 64);
    if (lane == 0) carry = (h == 0) ? xs[0] : 0.0f;

    // ---- cross-half carry: h0 publishes m[1023]; h1 adds decayed term ----
    if (h == 0 && lane == 63) carr[wb] = v;
    __syncthreads();
    if (h == 1) {
        const float m1023 = carr[wb];
        const float lng16 = __logf(g16);
        const float scale = __expf((float)lane * lng16);  // g^(16*lane)
        carry = fmaf(scale, m1023, carry);
    }

    // ---- fixup + pcen + LDS stage ----
    float* tw = tile + wb * PL + (h * 64 + lane) * 17;
    m = carry;
    #pragma unroll
    for (int k = 0; k < 16; ++k) {
        m = fmaf(g, m, s * xs[k]);                         // smoother[t]
        float lg     = LOG_EPS + __logf(fmaf(m, INV_EPS, 1.0f));
        float smooth = __expf(-a * lg);
        float base   = fmaf(xs[k], smooth, dd);
        float o      = __expf(rr * __logf(base)) - dpow;
        tw[k] = o;
    }
    __syncthreads();

    // ---- t-major coalesced write: out[b][t][band] ----
    // thread i: band-within-group wp = i&7, t offset tof = i>>3 (0..127)
    const int wp  = tid & 7;
    const int tof = tid >> 3;
    float* op = out + (size_t)b * T_LEN * NBANDS + bg * 8;
    #pragma unroll 4
    for (int c = 0; c < 16; ++c) {
        int t = c * 128 + tof;
        int l = t >> 4;
        int k = t & 15;
        op[(size_t)t * NBANDS + wp] = tile[wp * PL + l * 17 + k];
    }
}

extern "C" void kernel_launch(void* const* d_in, const int* in_sizes, int n_in,
                              void* d_out, int out_size, void* d_ws, size_t ws_size,
                              hipStream_t stream) {
    const float* x     = (const float*)d_in[0];
    const float* alpha = (const float*)d_in[1];
    const float* delta = (const float*)d_in[2];
    const float* r     = (const float*)d_in[3];
    float* out = (float*)d_out;

    // 16 batches x 16 band-groups(8 bands) = 256 blocks, 1024 threads (16 waves)
    hipLaunchKernelGGL(pcen_kernel, dim3(16 * 16), dim3(1024), 0, stream,
                       x, alpha, delta, r, out);
}